// Round 1
// baseline (122.999 us; speedup 1.0000x reference)
//
#include <hip/hip_runtime.h>
#include <hip/hip_bf16.h>

typedef __attribute__((ext_vector_type(8))) short short8;
typedef __attribute__((ext_vector_type(4))) float floatx4;

#define TINV 14.2857142857142857f   // 1/0.07
#define NROWS 8192
#define NDIM 128

__device__ __forceinline__ unsigned short f2bf(float f) {
    unsigned int u = __float_as_uint(f);
    u += 0x7fff + ((u >> 16) & 1);   // round-to-nearest-even
    return (unsigned short)(u >> 16);
}

__global__ void convert_kernel(const float* __restrict__ in, unsigned short* __restrict__ out) {
    int i = blockIdx.x * 256 + threadIdx.x;            // 262144 threads, 4 elems each
    float4 v = ((const float4*)in)[i];
    ushort4 o;
    o.x = f2bf(v.x); o.y = f2bf(v.y); o.z = f2bf(v.z); o.w = f2bf(v.w);
    ((ushort4*)out)[i] = o;
}

__global__ void pcount_kernel(const int* __restrict__ labels, float* __restrict__ pcount) {
    __shared__ int lab[512];
    int t = threadIdx.x;
    lab[t] = labels[t];
    __syncthreads();
    int my = lab[t], cnt = 0;
    #pragma unroll 8
    for (int b = 0; b < 512; ++b) cnt += (lab[b] == my) ? 1 : 0;
    pcount[t] = 16.0f * (float)(cnt - 1);              // positives per row of this batch
}

// 512 blocks: rb = blockIdx&63 (128 rows), q = blockIdx>>6 (1024-col chunk)
__global__ __launch_bounds__(256, 2) void supcon_main(
    const unsigned short* __restrict__ fb,
    const int* __restrict__ labels,
    float* __restrict__ stats,       // [8 chunks][8192 rows][3] : m, sumexp, possum
    float* __restrict__ noisep)      // [512] per-block noise partial
{
    __shared__ __align__(16) short stage[64 * 128];    // 16 KB column tile
    __shared__ float SM[2048], SS[2048], SP[2048];     // 24 KB: 128 rows x 16 lane-partials
    __shared__ float nred[256];
    __shared__ int clab[64];

    const int rb = blockIdx.x & 63;
    const int q  = blockIdx.x >> 6;
    const int rowBase = rb << 7;
    const int colBase = q << 10;
    const int tid = threadIdx.x;
    const int w = tid >> 6;
    const int lane = tid & 63;
    const int l15 = lane & 15;
    const int l4  = lane >> 4;

    if (tid < 64) clab[tid] = labels[(colBase >> 4) + tid];

    // A fragments: wave owns 32 rows = 2 rowsets of 16; K=128 resident in regs
    short8 afrag[2][4];
    int rw[2], brow[2], lrow[2];
    #pragma unroll
    for (int s = 0; s < 2; ++s) {
        rw[s]   = rowBase + w * 32 + s * 16;
        brow[s] = rw[s] >> 4;
        lrow[s] = labels[brow[s]];
        const short8* src = (const short8*)(fb + (size_t)(rw[s] + l15) * NDIM);
        #pragma unroll
        for (int t = 0; t < 4; ++t) afrag[s][t] = src[t * 4 + l4];
    }

    float m[2][4], su[2][4], ps[2][4];
    #pragma unroll
    for (int s = 0; s < 2; ++s)
        #pragma unroll
        for (int r = 0; r < 4; ++r) { m[s][r] = -1e30f; su[s][r] = 0.0f; ps[s][r] = 0.0f; }
    float noise_acc = 0.0f;

    const short8* stv = (const short8*)stage;

    for (int it = 0; it < 16; ++it) {
        __syncthreads();
        {   // stage 64 columns (rows of f), XOR-swizzled in 16B units
            const int col = tid >> 2;
            const int kb0 = (tid & 3) << 2;
            const short8* g = (const short8*)(fb + (size_t)(colBase + (it << 6) + col) * NDIM);
            short8* dst = (short8*)stage;
            const int sw = col & 15;
            #pragma unroll
            for (int i = 0; i < 4; ++i)
                dst[col * 16 + ((kb0 + i) ^ sw)] = g[kb0 + i];
        }
        __syncthreads();

        floatx4 vacc[2][4];
        #pragma unroll
        for (int c = 0; c < 4; ++c) {
            short8 bfrag[4];
            const int coll = c * 16 + l15;
            #pragma unroll
            for (int t = 0; t < 4; ++t)
                bfrag[t] = stv[coll * 16 + ((4 * t + l4) ^ l15)];
            #pragma unroll
            for (int s = 0; s < 2; ++s) {
                floatx4 acc = {0.0f, 0.0f, 0.0f, 0.0f};
                #pragma unroll
                for (int t = 0; t < 4; ++t)
                    acc = __builtin_amdgcn_mfma_f32_16x16x32_bf16(afrag[s][t], bfrag[t], acc, 0, 0, 0);
                vacc[s][c] = acc;
            }
        }

        // epilogue: masks are wave-uniform per (rowset, coltile)
        const int bq0 = (colBase >> 4) + (it << 2);
        #pragma unroll
        for (int s = 0; s < 2; ++s) {
            bool ntile[4], valid[4], pos[4];
            #pragma unroll
            for (int c = 0; c < 4; ++c) {
                ntile[c] = (bq0 + c) == brow[s];           // same batch: invalid + noise tile
                valid[c] = !ntile[c];
                pos[c]   = valid[c] && (clab[(it << 2) + c] == lrow[s]);
            }
            #pragma unroll
            for (int r = 0; r < 4; ++r) {
                float vv[4];
                #pragma unroll
                for (int c = 0; c < 4; ++c) vv[c] = vacc[s][c][r];
                float lmax = -1e30f;
                #pragma unroll
                for (int c = 0; c < 4; ++c) if (valid[c]) lmax = fmaxf(lmax, vv[c]);
                float nm = fmaxf(m[s][r], lmax);
                float alpha = __expf(TINV * (m[s][r] - nm));
                float acc = 0.0f;
                #pragma unroll
                for (int c = 0; c < 4; ++c) if (valid[c]) acc += __expf(TINV * (vv[c] - nm));
                su[s][r] = fmaf(su[s][r], alpha, acc);
                m[s][r] = nm;
                #pragma unroll
                for (int c = 0; c < 4; ++c) if (pos[c]) ps[s][r] += vv[c];
                #pragma unroll
                for (int c = 0; c < 4; ++c) if (ntile[c]) {
                    int row = rw[s] + l4 * 4 + r;
                    int col = colBase + (it << 6) + c * 16 + l15;
                    if ((row >> 3) == (col >> 3) && row != col) noise_acc += vv[c];
                }
            }
        }
    }

    // per-row combine of 16 lane-partials, write chunk partials
    __syncthreads();
    #pragma unroll
    for (int s = 0; s < 2; ++s)
        #pragma unroll
        for (int r = 0; r < 4; ++r) {
            int rl = w * 32 + s * 16 + l4 * 4 + r;
            SM[rl * 16 + l15] = m[s][r];
            SS[rl * 16 + l15] = su[s][r];
            SP[rl * 16 + l15] = ps[s][r];
        }
    nred[tid] = noise_acc;
    __syncthreads();
    if (tid < 128) {
        float gm = -1e30f;
        #pragma unroll
        for (int k = 0; k < 16; ++k) gm = fmaxf(gm, SM[tid * 16 + k]);
        float gs = 0.0f, gp = 0.0f;
        #pragma unroll
        for (int k = 0; k < 16; ++k) {
            gs += SS[tid * 16 + k] * __expf(TINV * (SM[tid * 16 + k] - gm));
            gp += SP[tid * 16 + k];
        }
        int rowg = rowBase + tid;
        float* o = stats + ((size_t)q * NROWS + rowg) * 3;
        o[0] = gm; o[1] = gs; o[2] = gp;
    }
    for (int off = 128; off > 0; off >>= 1) {
        if (tid < off) nred[tid] += nred[tid + off];
        __syncthreads();
    }
    if (tid == 0) noisep[blockIdx.x] = nred[0];
}

__global__ void final_kernel(const float* __restrict__ stats,
                             const float* __restrict__ noisep,
                             const float* __restrict__ pcount,
                             float* __restrict__ out)
{
    __shared__ float red[512];
    int t = threadIdx.x;
    float local = 0.0f;
    for (int i = t; i < NROWS; i += 512) {
        float mq[8], sq[8], pq[8];
        float gm = -1e30f;
        #pragma unroll
        for (int qq = 0; qq < 8; ++qq) {
            const float* o = stats + ((size_t)qq * NROWS + i) * 3;
            mq[qq] = o[0]; sq[qq] = o[1]; pq[qq] = o[2];
            gm = fmaxf(gm, mq[qq]);
        }
        float gs = 0.0f, gp = 0.0f;
        #pragma unroll
        for (int qq = 0; qq < 8; ++qq) {
            gs += sq[qq] * __expf(TINV * (mq[qq] - gm));
            gp += pq[qq];
        }
        float P = pcount[i >> 4];
        float term = (P * (TINV * gm + logf(gs)) - TINV * gp) / (P + 1e-8f);
        local += term;
    }
    float nlocal = noisep[t];  // 512 block partials, one per thread
    // loss = (loss_class + loss_noise)/3 ; loss_noise = -(TINV*noise_sum)/(57344*0.07)
    float contrib = local * (1.0f / (8192.0f * 3.0f))
                  + nlocal * (-TINV / (57344.0f * 0.07f * 3.0f));
    red[t] = contrib;
    __syncthreads();
    for (int off = 256; off > 0; off >>= 1) {
        if (t < off) red[t] += red[t + off];
        __syncthreads();
    }
    if (t == 0) out[0] = red[0];
}

extern "C" void kernel_launch(void* const* d_in, const int* in_sizes, int n_in,
                              void* d_out, int out_size, void* d_ws, size_t ws_size,
                              hipStream_t stream) {
    const float* feat  = (const float*)d_in[0];     // 8192 x 128 fp32
    const int* labels  = (const int*)d_in[1];       // 512 int32
    float* out = (float*)d_out;

    unsigned short* fb = (unsigned short*)d_ws;                      // 2 MB bf16 features
    float* wsf    = (float*)((char*)d_ws + (size_t)NROWS * NDIM * 2);
    float* stats  = wsf;                  // 8*8192*3 = 196608 floats
    float* noisep = wsf + 196608;         // 512 floats
    float* pcount = wsf + 197120;         // 512 floats

    hipLaunchKernelGGL(convert_kernel, dim3(1024), dim3(256), 0, stream, feat, fb);
    hipLaunchKernelGGL(pcount_kernel, dim3(1), dim3(512), 0, stream, labels, pcount);
    hipLaunchKernelGGL(supcon_main, dim3(512), dim3(256), 0, stream, fb, labels, stats, noisep);
    hipLaunchKernelGGL(final_kernel, dim3(1), dim3(512), 0, stream, stats, noisep, pcount, out);
}

// Round 2
// 113.655 us; speedup vs baseline: 1.0822x; 1.0822x over previous
//
#include <hip/hip_runtime.h>
#include <hip/hip_bf16.h>

typedef __attribute__((ext_vector_type(8))) short short8;
typedef __attribute__((ext_vector_type(4))) float floatx4;

#define TINV 14.2857142857142857f               // 1/0.07
#define TL2  20.60992915555662f                  // TINV * log2(e)
#define LN2  0.6931471805599453f
#define NROWS 8192
#define NDIM 128
#define NCH 16
#define NITS 8                                   // 8 x 64 cols = 512-col chunk

__device__ __forceinline__ float fexp2(float x) {
#if __has_builtin(__builtin_amdgcn_exp2f)
    return __builtin_amdgcn_exp2f(x);
#else
    return __expf(x * LN2);
#endif
}

__device__ __forceinline__ unsigned short f2bf(float f) {
    unsigned int u = __float_as_uint(f);
    u += 0x7fff + ((u >> 16) & 1);
    return (unsigned short)(u >> 16);
}

__global__ void convert_kernel(const float* __restrict__ in, unsigned short* __restrict__ out) {
    int i = blockIdx.x * 256 + threadIdx.x;
    float4 v = ((const float4*)in)[i];
    ushort4 o;
    o.x = f2bf(v.x); o.y = f2bf(v.y); o.z = f2bf(v.z); o.w = f2bf(v.w);
    ((ushort4*)out)[i] = o;
}

// grid 1024: rb = blockIdx&63 (128 rows), q = blockIdx>>6 (512-col chunk)
__global__ __launch_bounds__(256) void supcon_main(
    const unsigned short* __restrict__ fb,
    const int* __restrict__ labels,
    float* __restrict__ sM, float* __restrict__ sS, float* __restrict__ sP,
    float* __restrict__ noisep)
{
    // K-major staging: stage[kchunk 0..15][col 0..63] in short8 (16B) units = 16 KB
    __shared__ __align__(16) short stage[16 * 64 * 8];
    __shared__ int clab[32];
    __shared__ float nredW[4];

    const int rb = blockIdx.x & 63;
    const int q  = blockIdx.x >> 6;
    const int rowBase = rb << 7;
    const int colBase = q << 9;
    const int tid = threadIdx.x;
    const int w = tid >> 6;
    const int lane = tid & 63;
    const int l15 = lane & 15;
    const int l4  = lane >> 4;

    if (tid < 32) clab[tid] = labels[(colBase >> 4) + tid];

    // A fragments: wave owns 32 rows = 2 rowsets of 16, K=128 register-resident
    short8 afrag[2][4];
    int rw[2], brow[2], lrow[2];
    #pragma unroll
    for (int s = 0; s < 2; ++s) {
        rw[s]   = rowBase + w * 32 + s * 16;
        brow[s] = rw[s] >> 4;
        lrow[s] = labels[brow[s]];
        const short8* src = (const short8*)(fb + (size_t)(rw[s] + l15) * NDIM);
        #pragma unroll
        for (int t = 0; t < 4; ++t) afrag[s][t] = src[t * 4 + l4];
    }

    float tm[2][4], su[2][4], ps[2][4];
    #pragma unroll
    for (int s = 0; s < 2; ++s)
        #pragma unroll
        for (int r = 0; r < 4; ++r) { tm[s][r] = -1e30f; su[s][r] = 0.0f; ps[s][r] = 0.0f; }
    float noise_acc = 0.0f;

    const short8* stv = (const short8*)stage;

    for (int it = 0; it < NITS; ++it) {
        __syncthreads();
        {   // async global -> LDS, K-major: one 1KB row (64 cols x 16B) per instr
            const unsigned short* gcol = fb + (size_t)(colBase + (it << 6) + lane) * NDIM;
            unsigned short* lbase = (unsigned short*)stage;
            #pragma unroll
            for (int j = 0; j < 4; ++j) {
                const int kc = (w << 2) + j;
                __builtin_amdgcn_global_load_lds(
                    (const __attribute__((address_space(1))) unsigned int*)(gcol + kc * 8),
                    (__attribute__((address_space(3))) unsigned int*)(lbase + kc * 512),
                    16, 0, 0);
            }
        }
        __syncthreads();

        floatx4 vacc[2][4];
        #pragma unroll
        for (int c = 0; c < 4; ++c) {
            short8 bfrag[4];
            #pragma unroll
            for (int t = 0; t < 4; ++t)
                bfrag[t] = stv[(t * 4 + l4) * 64 + c * 16 + l15];   // conflict-free
            #pragma unroll
            for (int s = 0; s < 2; ++s) {
                floatx4 acc = {0.0f, 0.0f, 0.0f, 0.0f};
                #pragma unroll
                for (int t = 0; t < 4; ++t)
                    acc = __builtin_amdgcn_mfma_f32_16x16x32_bf16(afrag[s][t], bfrag[t], acc, 0, 0, 0);
                vacc[s][c] = acc;
            }
        }

        const int bq0 = (colBase >> 4) + (it << 2);
        const int cl0 = clab[(it << 2) + 0], cl1 = clab[(it << 2) + 1];
        const int cl2 = clab[(it << 2) + 2], cl3 = clab[(it << 2) + 3];
        #pragma unroll
        for (int s = 0; s < 2; ++s) {
            const int nt = brow[s] - bq0;          // noise tile index if in [0,4)
            const bool anyn = ((unsigned)nt) < 4u; // wave-uniform
            int posm = 0;
            if (cl0 == lrow[s] && nt != 0) posm |= 1;
            if (cl1 == lrow[s] && nt != 1) posm |= 2;
            if (cl2 == lrow[s] && nt != 2) posm |= 4;
            if (cl3 == lrow[s] && nt != 3) posm |= 8;
            #pragma unroll
            for (int r = 0; r < 4; ++r) {
                const float v0 = vacc[s][0][r], v1 = vacc[s][1][r];
                const float v2 = vacc[s][2][r], v3 = vacc[s][3][r];
                if (!anyn) {
                    // fast path: all 4 tiles valid, no per-element conditionals
                    float tmax = fmaxf(fmaxf(v0, v1), fmaxf(v2, v3)) * TL2;
                    float tmr = tm[s][r];
                    float tnm = fmaxf(tmr, tmax);
                    float alpha = fexp2(tmr - tnm);
                    float e0 = fexp2(fmaf(TL2, v0, -tnm));
                    float e1 = fexp2(fmaf(TL2, v1, -tnm));
                    float e2 = fexp2(fmaf(TL2, v2, -tnm));
                    float e3 = fexp2(fmaf(TL2, v3, -tnm));
                    su[s][r] = fmaf(su[s][r], alpha, (e0 + e1) + (e2 + e3));
                    tm[s][r] = tnm;
                } else {
                    // rare path: one tile is the same-batch (invalid/noise) tile
                    float m3 = -1e30f;
                    if (nt != 0) m3 = fmaxf(m3, v0);
                    if (nt != 1) m3 = fmaxf(m3, v1);
                    if (nt != 2) m3 = fmaxf(m3, v2);
                    if (nt != 3) m3 = fmaxf(m3, v3);
                    m3 *= TL2;
                    float tmr = tm[s][r];
                    float tnm = fmaxf(tmr, m3);
                    float alpha = fexp2(tmr - tnm);
                    float acc4 = 0.0f;
                    if (nt != 0) acc4 += fexp2(fmaf(TL2, v0, -tnm));
                    if (nt != 1) acc4 += fexp2(fmaf(TL2, v1, -tnm));
                    if (nt != 2) acc4 += fexp2(fmaf(TL2, v2, -tnm));
                    if (nt != 3) acc4 += fexp2(fmaf(TL2, v3, -tnm));
                    su[s][r] = fmaf(su[s][r], alpha, acc4);
                    tm[s][r] = tnm;
                    // noise pairs live in the diagonal batch tile
                    float vn = (nt == 0) ? v0 : (nt == 1) ? v1 : (nt == 2) ? v2 : v3;
                    int rl = (l4 << 2) + r;
                    if ((rl >> 3) == (l15 >> 3) && rl != l15) noise_acc += vn;
                }
                if (posm) {
                    if (posm & 1) ps[s][r] += v0;
                    if (posm & 2) ps[s][r] += v1;
                    if (posm & 4) ps[s][r] += v2;
                    if (posm & 8) ps[s][r] += v3;
                }
            }
        }
    }

    // combine the 16 lane-partials per row via shuffles (lanes l15=0..15 hold one row)
    #pragma unroll
    for (int s = 0; s < 2; ++s)
        #pragma unroll
        for (int r = 0; r < 4; ++r) {
            float tmv = tm[s][r], suv = su[s][r], psv = ps[s][r];
            #pragma unroll
            for (int off = 1; off < 16; off <<= 1) {
                float om = __shfl_xor(tmv, off);
                float os = __shfl_xor(suv, off);
                float op = __shfl_xor(psv, off);
                float nm = fmaxf(tmv, om);
                suv = suv * fexp2(tmv - nm) + os * fexp2(om - nm);
                tmv = nm; psv += op;
            }
            if (l15 == 0) {
                int row = rw[s] + (l4 << 2) + r;
                sM[row * NCH + q] = tmv;
                sS[row * NCH + q] = suv;
                sP[row * NCH + q] = psv;
            }
        }

    float na = noise_acc;
    #pragma unroll
    for (int off = 32; off >= 1; off >>= 1) na += __shfl_xor(na, off);
    if (lane == 0) nredW[w] = na;
    __syncthreads();
    if (tid == 0) noisep[blockIdx.x] = nredW[0] + nredW[1] + nredW[2] + nredW[3];
}

// 64 blocks x 128 threads: per-row chunk merge + class term; pcount inline
__global__ __launch_bounds__(128) void final_a(
    const float* __restrict__ sM, const float* __restrict__ sS, const float* __restrict__ sP,
    const int* __restrict__ labels, float* __restrict__ classp)
{
    __shared__ int lab[512];
    __shared__ float pc[8];
    __shared__ float red[128];
    const int tid = threadIdx.x;
    #pragma unroll
    for (int j = 0; j < 4; ++j) lab[tid + 128 * j] = labels[tid + 128 * j];
    __syncthreads();
    if (tid < 8) {
        int b = blockIdx.x * 8 + tid;
        int my = lab[b], cnt = 0;
        for (int k = 0; k < 512; ++k) cnt += (lab[k] == my) ? 1 : 0;
        pc[tid] = 16.0f * (float)(cnt - 1);
    }
    __syncthreads();
    const int row = blockIdx.x * 128 + tid;
    float mq[NCH], sq[NCH], pq[NCH];
    const float4* M4 = (const float4*)(sM + (size_t)row * NCH);
    const float4* S4 = (const float4*)(sS + (size_t)row * NCH);
    const float4* P4 = (const float4*)(sP + (size_t)row * NCH);
    #pragma unroll
    for (int j = 0; j < 4; ++j) {
        float4 a = M4[j]; mq[4*j] = a.x; mq[4*j+1] = a.y; mq[4*j+2] = a.z; mq[4*j+3] = a.w;
        float4 b = S4[j]; sq[4*j] = b.x; sq[4*j+1] = b.y; sq[4*j+2] = b.z; sq[4*j+3] = b.w;
        float4 c = P4[j]; pq[4*j] = c.x; pq[4*j+1] = c.y; pq[4*j+2] = c.z; pq[4*j+3] = c.w;
    }
    float gm = -1e30f;
    #pragma unroll
    for (int qq = 0; qq < NCH; ++qq) gm = fmaxf(gm, mq[qq]);
    float gs = 0.0f, gp = 0.0f;
    #pragma unroll
    for (int qq = 0; qq < NCH; ++qq) { gs += sq[qq] * fexp2(mq[qq] - gm); gp += pq[qq]; }
    const float P = pc[tid >> 4];
    // L = ln(sum exp(TINV*v)) = ln2 * (gm + log2(gs));  term = (P*L - TINV*possum)/(P+1e-8)
    const float term = (P * (LN2 * (gm + __log2f(gs))) - TINV * gp) / (P + 1e-8f);
    red[tid] = term;
    __syncthreads();
    #pragma unroll
    for (int off = 64; off > 0; off >>= 1) {
        if (tid < off) red[tid] += red[tid + off];
        __syncthreads();
    }
    if (tid == 0) classp[blockIdx.x] = red[0];
}

__global__ void final_b(const float* __restrict__ classp, const float* __restrict__ noisep,
                        float* __restrict__ out)
{
    __shared__ float red[512];
    const int t = threadIdx.x;
    float c = (t < 64) ? classp[t] : 0.0f;
    float n = noisep[t] + noisep[t + 512];
    red[t] = c * (1.0f / (8192.0f * 3.0f)) + n * (-TINV / (57344.0f * 0.07f * 3.0f));
    __syncthreads();
    for (int off = 256; off > 0; off >>= 1) {
        if (t < off) red[t] += red[t + off];
        __syncthreads();
    }
    if (t == 0) out[0] = red[0];
}

extern "C" void kernel_launch(void* const* d_in, const int* in_sizes, int n_in,
                              void* d_out, int out_size, void* d_ws, size_t ws_size,
                              hipStream_t stream) {
    const float* feat  = (const float*)d_in[0];
    const int* labels  = (const int*)d_in[1];
    float* out = (float*)d_out;

    unsigned short* fb = (unsigned short*)d_ws;                        // 2 MB bf16
    float* wsf   = (float*)((char*)d_ws + (size_t)NROWS * NDIM * 2);
    float* sM     = wsf;                   // 8192*16
    float* sS     = wsf + 131072;
    float* sP     = wsf + 262144;
    float* noisep = wsf + 393216;          // 1024
    float* classp = wsf + 394240;          // 64

    hipLaunchKernelGGL(convert_kernel, dim3(1024), dim3(256), 0, stream, feat, fb);
    hipLaunchKernelGGL(supcon_main, dim3(1024), dim3(256), 0, stream, fb, labels, sM, sS, sP, noisep);
    hipLaunchKernelGGL(final_a, dim3(64), dim3(128), 0, stream, sM, sS, sP, labels, classp);
    hipLaunchKernelGGL(final_b, dim3(1), dim3(512), 0, stream, classp, noisep, out);
}

// Round 3
// 109.988 us; speedup vs baseline: 1.1183x; 1.0333x over previous
//
#include <hip/hip_runtime.h>
#include <hip/hip_bf16.h>

typedef __attribute__((ext_vector_type(8))) short short8;
typedef __attribute__((ext_vector_type(4))) float floatx4;

#define TINV 14.2857142857142857f               // 1/0.07
#define TL2  20.60992915555662f                  // TINV * log2(e)
#define LN2  0.6931471805599453f
#define NROWS 8192
#define NDIM 128
#define NCH 16
#define NITS 8                                   // 8 x 64 cols = 512-col chunk

__device__ __forceinline__ float fexp2(float x) {
#if __has_builtin(__builtin_amdgcn_exp2f)
    return __builtin_amdgcn_exp2f(x);
#else
    return __expf(x * LN2);
#endif
}

__device__ __forceinline__ short8 pack8(float4 a, float4 b) {
    union { short8 s; __hip_bfloat162 h[4]; } u;
    u.h[0] = __float22bfloat162_rn(float2{a.x, a.y});
    u.h[1] = __float22bfloat162_rn(float2{a.z, a.w});
    u.h[2] = __float22bfloat162_rn(float2{b.x, b.y});
    u.h[3] = __float22bfloat162_rn(float2{b.z, b.w});
    return u.s;
}

// grid 1024: rb = blockIdx&63 (128 rows), q = blockIdx>>6 (512-col chunk)
// fp32 input; bf16 conversion fused into staging (VGPR round-trip, double-buffered LDS)
__global__ __launch_bounds__(256) void supcon_main(
    const float* __restrict__ feat,
    const int* __restrict__ labels,
    float* __restrict__ sM, float* __restrict__ sS, float* __restrict__ sP,
    float* __restrict__ noisep)
{
    // K-major staging: stage[buf][kchunk 0..15][col 0..63] in short8 units, 2 x 16 KB
    __shared__ __align__(16) short stage[2][16 * 64 * 8];
    __shared__ int clab[32];
    __shared__ float nredW[4];

    const int rb = blockIdx.x & 63;
    const int q  = blockIdx.x >> 6;
    const int rowBase = rb << 7;
    const int colBase = q << 9;
    const int tid = threadIdx.x;
    const int w = tid >> 6;
    const int lane = tid & 63;
    const int l15 = lane & 15;
    const int l4  = lane >> 4;

    // ---- prologue: issue staging loads for it=0 first (latency overlap) ----
    float4 g[8];
    {
        const float4* gp = (const float4*)(feat + (size_t)(colBase + lane) * NDIM);
        #pragma unroll
        for (int j = 0; j < 4; ++j) {
            const int kc = (w << 2) + j;
            g[2 * j]     = gp[kc * 2];
            g[2 * j + 1] = gp[kc * 2 + 1];
        }
    }

    if (tid < 32) clab[tid] = labels[(colBase >> 4) + tid];

    // A fragments: wave owns 32 rows = 2 rowsets of 16; convert fp32->bf16 in regs
    short8 afrag[2][4];
    int rw[2], brow[2], lrow[2];
    #pragma unroll
    for (int s = 0; s < 2; ++s) {
        rw[s]   = rowBase + w * 32 + s * 16;
        brow[s] = rw[s] >> 4;
        lrow[s] = labels[brow[s]];
        const float4* src = (const float4*)(feat + (size_t)(rw[s] + l15) * NDIM);
        #pragma unroll
        for (int t = 0; t < 4; ++t)
            afrag[s][t] = pack8(src[t * 8 + l4 * 2], src[t * 8 + l4 * 2 + 1]);
    }

    {   // write it=0 tile
        short8* dst = (short8*)stage[0];
        #pragma unroll
        for (int j = 0; j < 4; ++j) {
            const int kc = (w << 2) + j;
            dst[kc * 64 + lane] = pack8(g[2 * j], g[2 * j + 1]);
        }
    }

    float tm[2][4], su[2][4], ps[2][4];
    #pragma unroll
    for (int s = 0; s < 2; ++s)
        #pragma unroll
        for (int r = 0; r < 4; ++r) { tm[s][r] = -1e30f; su[s][r] = 0.0f; ps[s][r] = 0.0f; }
    float noise_acc = 0.0f;

    __syncthreads();

    for (int it = 0; it < NITS; ++it) {
        const short8* stv = (const short8*)stage[it & 1];

        // issue next tile's global loads NOW; vmcnt wait lands after compute
        if (it + 1 < NITS) {
            const float4* gp = (const float4*)(feat + (size_t)(colBase + ((it + 1) << 6) + lane) * NDIM);
            #pragma unroll
            for (int j = 0; j < 4; ++j) {
                const int kc = (w << 2) + j;
                g[2 * j]     = gp[kc * 2];
                g[2 * j + 1] = gp[kc * 2 + 1];
            }
        }

        floatx4 vacc[2][4];
        #pragma unroll
        for (int c = 0; c < 4; ++c) {
            short8 bfrag[4];
            #pragma unroll
            for (int t = 0; t < 4; ++t)
                bfrag[t] = stv[(t * 4 + l4) * 64 + c * 16 + l15];   // conflict-free
            #pragma unroll
            for (int s = 0; s < 2; ++s) {
                floatx4 acc = {0.0f, 0.0f, 0.0f, 0.0f};
                #pragma unroll
                for (int t = 0; t < 4; ++t)
                    acc = __builtin_amdgcn_mfma_f32_16x16x32_bf16(afrag[s][t], bfrag[t], acc, 0, 0, 0);
                vacc[s][c] = acc;
            }
        }

        const int bq0 = (colBase >> 4) + (it << 2);
        const int cl0 = clab[(it << 2) + 0], cl1 = clab[(it << 2) + 1];
        const int cl2 = clab[(it << 2) + 2], cl3 = clab[(it << 2) + 3];
        #pragma unroll
        for (int s = 0; s < 2; ++s) {
            const int nt = brow[s] - bq0;          // noise-tile index if in [0,4)
            const bool anyn = ((unsigned)nt) < 4u; // wave-uniform
            int posm = 0;
            if (cl0 == lrow[s] && nt != 0) posm |= 1;
            if (cl1 == lrow[s] && nt != 1) posm |= 2;
            if (cl2 == lrow[s] && nt != 2) posm |= 4;
            if (cl3 == lrow[s] && nt != 3) posm |= 8;
            #pragma unroll
            for (int r = 0; r < 4; ++r) {
                const float v0 = vacc[s][0][r], v1 = vacc[s][1][r];
                const float v2 = vacc[s][2][r], v3 = vacc[s][3][r];
                if (!anyn) {
                    float tmax = fmaxf(fmaxf(v0, v1), fmaxf(v2, v3)) * TL2;
                    float tmr = tm[s][r];
                    float tnm = fmaxf(tmr, tmax);
                    float alpha = fexp2(tmr - tnm);
                    float e0 = fexp2(fmaf(TL2, v0, -tnm));
                    float e1 = fexp2(fmaf(TL2, v1, -tnm));
                    float e2 = fexp2(fmaf(TL2, v2, -tnm));
                    float e3 = fexp2(fmaf(TL2, v3, -tnm));
                    su[s][r] = fmaf(su[s][r], alpha, (e0 + e1) + (e2 + e3));
                    tm[s][r] = tnm;
                } else {
                    float m3 = -1e30f;
                    if (nt != 0) m3 = fmaxf(m3, v0);
                    if (nt != 1) m3 = fmaxf(m3, v1);
                    if (nt != 2) m3 = fmaxf(m3, v2);
                    if (nt != 3) m3 = fmaxf(m3, v3);
                    m3 *= TL2;
                    float tmr = tm[s][r];
                    float tnm = fmaxf(tmr, m3);
                    float alpha = fexp2(tmr - tnm);
                    float acc4 = 0.0f;
                    if (nt != 0) acc4 += fexp2(fmaf(TL2, v0, -tnm));
                    if (nt != 1) acc4 += fexp2(fmaf(TL2, v1, -tnm));
                    if (nt != 2) acc4 += fexp2(fmaf(TL2, v2, -tnm));
                    if (nt != 3) acc4 += fexp2(fmaf(TL2, v3, -tnm));
                    su[s][r] = fmaf(su[s][r], alpha, acc4);
                    tm[s][r] = tnm;
                    float vn = (nt == 0) ? v0 : (nt == 1) ? v1 : (nt == 2) ? v2 : v3;
                    int rl = (l4 << 2) + r;
                    if ((rl >> 3) == (l15 >> 3) && rl != l15) noise_acc += vn;
                }
                if (posm) {
                    if (posm & 1) ps[s][r] += v0;
                    if (posm & 2) ps[s][r] += v1;
                    if (posm & 4) ps[s][r] += v2;
                    if (posm & 8) ps[s][r] += v3;
                }
            }
        }

        // pack + write next tile into the other buffer (waits on vmcnt here)
        if (it + 1 < NITS) {
            short8* dst = (short8*)stage[(it + 1) & 1];
            #pragma unroll
            for (int j = 0; j < 4; ++j) {
                const int kc = (w << 2) + j;
                dst[kc * 64 + lane] = pack8(g[2 * j], g[2 * j + 1]);
            }
        }
        __syncthreads();
    }

    // combine 16 lane-partials per row via shuffles
    #pragma unroll
    for (int s = 0; s < 2; ++s)
        #pragma unroll
        for (int r = 0; r < 4; ++r) {
            float tmv = tm[s][r], suv = su[s][r], psv = ps[s][r];
            #pragma unroll
            for (int off = 1; off < 16; off <<= 1) {
                float om = __shfl_xor(tmv, off);
                float os = __shfl_xor(suv, off);
                float op = __shfl_xor(psv, off);
                float nm = fmaxf(tmv, om);
                suv = suv * fexp2(tmv - nm) + os * fexp2(om - nm);
                tmv = nm; psv += op;
            }
            if (l15 == 0) {
                int row = rw[s] + (l4 << 2) + r;
                sM[row * NCH + q] = tmv;
                sS[row * NCH + q] = suv;
                sP[row * NCH + q] = psv;
            }
        }

    float na = noise_acc;
    #pragma unroll
    for (int off = 32; off >= 1; off >>= 1) na += __shfl_xor(na, off);
    if (lane == 0) nredW[w] = na;
    __syncthreads();
    if (tid == 0) noisep[blockIdx.x] = nredW[0] + nredW[1] + nredW[2] + nredW[3];
}

// 32 blocks x 256 threads: per-row chunk merge + class term + noise; atomicAdd to out
__global__ __launch_bounds__(256) void final_k(
    const float* __restrict__ sM, const float* __restrict__ sS, const float* __restrict__ sP,
    const int* __restrict__ labels, const float* __restrict__ noisep,
    float* __restrict__ out)
{
    __shared__ int lab[512];
    __shared__ int hist[16];
    __shared__ float red[256];
    const int tid = threadIdx.x;
    if (tid < 16) hist[tid] = 0;
    lab[tid] = labels[tid];
    lab[tid + 256] = labels[tid + 256];
    __syncthreads();
    atomicAdd(&hist[lab[tid] & 15], 1);
    atomicAdd(&hist[lab[tid + 256] & 15], 1);
    __syncthreads();

    const int row = blockIdx.x * 256 + tid;
    float mq[NCH], sq[NCH], pq[NCH];
    const float4* M4 = (const float4*)(sM + (size_t)row * NCH);
    const float4* S4 = (const float4*)(sS + (size_t)row * NCH);
    const float4* P4 = (const float4*)(sP + (size_t)row * NCH);
    #pragma unroll
    for (int j = 0; j < 4; ++j) {
        float4 a = M4[j]; mq[4*j] = a.x; mq[4*j+1] = a.y; mq[4*j+2] = a.z; mq[4*j+3] = a.w;
        float4 b = S4[j]; sq[4*j] = b.x; sq[4*j+1] = b.y; sq[4*j+2] = b.z; sq[4*j+3] = b.w;
        float4 c = P4[j]; pq[4*j] = c.x; pq[4*j+1] = c.y; pq[4*j+2] = c.z; pq[4*j+3] = c.w;
    }
    float gm = -1e30f;
    #pragma unroll
    for (int qq = 0; qq < NCH; ++qq) gm = fmaxf(gm, mq[qq]);
    float gs = 0.0f, gp = 0.0f;
    #pragma unroll
    for (int qq = 0; qq < NCH; ++qq) { gs += sq[qq] * fexp2(mq[qq] - gm); gp += pq[qq]; }
    const float P = 16.0f * (float)(hist[lab[row >> 4] & 15] - 1);
    const float term = (P * (LN2 * (gm + __log2f(gs))) - TINV * gp) / (P + 1e-8f);

    float contrib = term * (1.0f / (8192.0f * 3.0f));
    if (tid < 32) contrib += noisep[blockIdx.x * 32 + tid] * (-TINV / (57344.0f * 0.07f * 3.0f));
    red[tid] = contrib;
    __syncthreads();
    #pragma unroll
    for (int off = 128; off > 0; off >>= 1) {
        if (tid < off) red[tid] += red[tid + off];
        __syncthreads();
    }
    if (tid == 0) atomicAdd(out, red[0]);
}

extern "C" void kernel_launch(void* const* d_in, const int* in_sizes, int n_in,
                              void* d_out, int out_size, void* d_ws, size_t ws_size,
                              hipStream_t stream) {
    const float* feat  = (const float*)d_in[0];
    const int* labels  = (const int*)d_in[1];
    float* out = (float*)d_out;

    float* wsf    = (float*)d_ws;
    float* sM     = wsf;                   // 8192*16
    float* sS     = wsf + 131072;
    float* sP     = wsf + 262144;
    float* noisep = wsf + 393216;          // 1024

    hipMemsetAsync(out, 0, sizeof(float), stream);
    hipLaunchKernelGGL(supcon_main, dim3(1024), dim3(256), 0, stream, feat, labels, sM, sS, sP, noisep);
    hipLaunchKernelGGL(final_k, dim3(32), dim3(256), 0, stream, sM, sS, sP, labels, noisep, out);
}